// Round 1
// baseline (2072.521 us; speedup 1.0000x reference)
//
#include <hip/hip_runtime.h>
#include <float.h>

// VectorQuantizer: N=32768 points, K=8192 codes, D=256, f32.
// d2 = (||x||^2 - 2 x.e) + ||e||^2 with f32 roundings replicated to match the
// numpy reference's quantization (d2 ~ 256 -> ulp 3e-5 dominates tie behavior).
// Out layout (f32): quantized_st [N*D] | loss_c | loss_d | mapping_inds [N]

#define NN 32768
#define KK 8192
#define DD 256
#define CSPLIT 4
#define BM 128   // rows per block tile
#define BN 128   // codes per code tile
#define KT 32    // k-chunk staged in LDS
#define TPB 256

// ws layout in floats: enorm[KK] | xnorm[NN] | candv[NN*CSPLIT] | candi[NN*CSPLIT] | loss[1]
#define WSF_ENORM 0
#define WSF_XNORM (KK)
#define WSF_CANDV (KK + NN)
#define WSF_CANDI (KK + NN + NN*CSPLIT)
#define WSF_LOSS  (KK + NN + 2*NN*CSPLIT)

__global__ __launch_bounds__(256) void vq_norms(const float* __restrict__ x,
                                                const float* __restrict__ emb,
                                                float* __restrict__ ws) {
  int gid = blockIdx.x * blockDim.x + threadIdx.x;
  int wave = gid >> 6, lane = gid & 63;
  const float* src;
  float* dst;
  if (wave < KK) {
    src = emb + (size_t)wave * DD;
    dst = ws + WSF_ENORM + wave;
  } else {
    int r = wave - KK;
    if (r >= NN) return;
    src = x + (size_t)r * DD;
    dst = ws + WSF_XNORM + r;
  }
  float4 v = ((const float4*)src)[lane];
  float s = v.x * v.x + v.y * v.y + v.z * v.z + v.w * v.w;
#pragma unroll
  for (int off = 32; off > 0; off >>= 1) s += __shfl_down(s, off, 64);
  if (lane == 0) *dst = s;
}

__global__ __launch_bounds__(256) void vq_argmin(const float* __restrict__ x,
                                                 const float* __restrict__ emb,
                                                 float* __restrict__ ws) {
  const float* enorm = ws + WSF_ENORM;
  const float* xnorm = ws + WSF_XNORM;
  float* candv = ws + WSF_CANDV;
  int* candi = (int*)(ws + WSF_CANDI);

  __shared__ float As[KT][BM + 4];  // As[kk][row] (transposed), stride 132: b128-aligned rows
  __shared__ float Bs[KT][BN + 4];  // Bs[kk][code]

  const int tid = threadIdx.x;
  const int tr = tid >> 4, tc = tid & 15;  // 16x16 thread grid, 8x8 micro-tile
  const int r0 = blockIdx.x * BM;
  const int split = blockIdx.y;
  const int cbase = split * (KK / CSPLIT);

  float xr[8];
  {
    const float4* p = (const float4*)(xnorm + r0 + tr * 8);
    float4 a = p[0], b = p[1];
    xr[0] = a.x; xr[1] = a.y; xr[2] = a.z; xr[3] = a.w;
    xr[4] = b.x; xr[5] = b.y; xr[6] = b.z; xr[7] = b.w;
  }

  float bestv[8];
  int besti[8];
#pragma unroll
  for (int i = 0; i < 8; i++) { bestv[i] = FLT_MAX; besti[i] = 0; }

  for (int ct = 0; ct < (KK / CSPLIT) / BN; ++ct) {
    const int c0 = cbase + ct * BN;
    float acc[8][8];
#pragma unroll
    for (int i = 0; i < 8; i++)
#pragma unroll
      for (int j = 0; j < 8; j++) acc[i][j] = 0.f;

    for (int kc = 0; kc < DD; kc += KT) {
      __syncthreads();
      {  // stage A (x) and B (emb) K-chunk, transposed into LDS
        const int rrow = tid >> 3, dg = tid & 7;
#pragma unroll
        for (int p = 0; p < 4; ++p) {
          int rw = p * 32 + rrow;
          float4 av = ((const float4*)(x + (size_t)(r0 + rw) * DD + kc))[dg];
          float4 bv = ((const float4*)(emb + (size_t)(c0 + rw) * DD + kc))[dg];
          As[dg * 4 + 0][rw] = av.x; As[dg * 4 + 1][rw] = av.y;
          As[dg * 4 + 2][rw] = av.z; As[dg * 4 + 3][rw] = av.w;
          Bs[dg * 4 + 0][rw] = bv.x; Bs[dg * 4 + 1][rw] = bv.y;
          Bs[dg * 4 + 2][rw] = bv.z; Bs[dg * 4 + 3][rw] = bv.w;
        }
      }
      __syncthreads();
#pragma unroll 4
      for (int kk = 0; kk < KT; ++kk) {
        float4 a0 = *(const float4*)&As[kk][tr * 8];
        float4 a1 = *(const float4*)&As[kk][tr * 8 + 4];
        float4 b0 = *(const float4*)&Bs[kk][tc * 8];
        float4 b1 = *(const float4*)&Bs[kk][tc * 8 + 4];
        float a[8] = {a0.x, a0.y, a0.z, a0.w, a1.x, a1.y, a1.z, a1.w};
        float b[8] = {b0.x, b0.y, b0.z, b0.w, b1.x, b1.y, b1.z, b1.w};
#pragma unroll
        for (int i = 0; i < 8; i++)
#pragma unroll
          for (int j = 0; j < 8; j++) acc[i][j] = fmaf(a[i], b[j], acc[i][j]);
      }
    }

    // epilogue: d2 = fl(fl(xx - 2*dot) + ee), matching numpy's rounding order
    float en[8];
    {
      const float4* p = (const float4*)(enorm + c0 + tc * 8);
      float4 a = p[0], b = p[1];
      en[0] = a.x; en[1] = a.y; en[2] = a.z; en[3] = a.w;
      en[4] = b.x; en[5] = b.y; en[6] = b.z; en[7] = b.w;
    }
#pragma unroll
    for (int i = 0; i < 8; i++) {
#pragma unroll
      for (int j = 0; j < 8; j++) {
        float t = fmaf(-2.f, acc[i][j], xr[i]);  // single rounding == xx - (2*M)
        float d2 = t + en[j];
        int code = c0 + tc * 8 + j;
        if (d2 < bestv[i]) { bestv[i] = d2; besti[i] = code; }  // strict <: first-min wins
      }
    }
  }

  // cross-tc reduction within wave (lane = (tr&3)*16 + tc)
#pragma unroll
  for (int i = 0; i < 8; i++) {
    float v = bestv[i];
    int bi = besti[i];
#pragma unroll
    for (int off = 1; off < 16; off <<= 1) {
      float v2 = __shfl_xor(v, off, 64);
      int i2 = __shfl_xor(bi, off, 64);
      if (v2 < v || (v2 == v && i2 < bi)) { v = v2; bi = i2; }
    }
    if (tc == 0) {
      int row = r0 + tr * 8 + i;
      candv[row * CSPLIT + split] = v;
      candi[row * CSPLIT + split] = bi;
    }
  }
}

__global__ __launch_bounds__(256) void vq_gather(const float* __restrict__ x,
                                                 const float* __restrict__ emb,
                                                 float* __restrict__ ws,
                                                 float* __restrict__ out) {
  const float* candv = ws + WSF_CANDV;
  const int* candi = (const int*)(ws + WSF_CANDI);
  float* loss_acc = ws + WSF_LOSS;

  int gid = blockIdx.x * blockDim.x + threadIdx.x;
  int row = gid >> 6, lane = gid & 63;
  if (row >= NN) return;

  float bv = candv[row * CSPLIT];
  int bi = candi[row * CSPLIT];
#pragma unroll
  for (int s = 1; s < CSPLIT; s++) {
    float v = candv[row * CSPLIT + s];
    int ii = candi[row * CSPLIT + s];
    if (v < bv || (v == bv && ii < bi)) { bv = v; bi = ii; }
  }
  if (lane == 0) out[(size_t)NN * DD + 2 + row] = (float)bi;

  float4 q = ((const float4*)(emb + (size_t)bi * DD))[lane];
  float4 xv = ((const float4*)(x + (size_t)row * DD))[lane];
  // straight-through value: x + (q - x), f32 ops mimicking the reference
  float4 st;
  st.x = xv.x + (q.x - xv.x);
  st.y = xv.y + (q.y - xv.y);
  st.z = xv.z + (q.z - xv.z);
  st.w = xv.w + (q.w - xv.w);
  ((float4*)(out + (size_t)row * DD))[lane] = st;

  float dx = xv.x - q.x, dy = xv.y - q.y, dz = xv.z - q.z, dw = xv.w - q.w;
  float s2 = dx * dx + dy * dy + dz * dz + dw * dw;
#pragma unroll
  for (int off = 32; off > 0; off >>= 1) s2 += __shfl_down(s2, off, 64);
  if (lane == 0) atomicAdd(loss_acc, s2);
}

__global__ void vq_finalize(const float* __restrict__ ws, float* __restrict__ out) {
  float loss = ws[WSF_LOSS] / (float)((size_t)NN * DD);
  out[(size_t)NN * DD] = loss;
  out[(size_t)NN * DD + 1] = loss;
}

extern "C" void kernel_launch(void* const* d_in, const int* in_sizes, int n_in,
                              void* d_out, int out_size, void* d_ws, size_t ws_size,
                              hipStream_t stream) {
  const float* x = (const float*)d_in[0];
  const float* emb = (const float*)d_in[1];
  float* out = (float*)d_out;
  float* ws = (float*)d_ws;

  // zero the loss accumulator (only ws state that is accumulated into)
  hipMemsetAsync((char*)d_ws + (size_t)WSF_LOSS * 4, 0, 4, stream);

  int nwaves = KK + NN;
  vq_norms<<<dim3((nwaves * 64 + 255) / 256), 256, 0, stream>>>(x, emb, ws);
  vq_argmin<<<dim3(NN / BM, CSPLIT), TPB, 0, stream>>>(x, emb, ws);
  vq_gather<<<dim3((NN * 64 + TPB - 1) / TPB), TPB, 0, stream>>>(x, emb, ws, out);
  vq_finalize<<<1, 1, 0, stream>>>(ws, out);
}